// Round 1
// baseline (1402.052 us; speedup 1.0000x reference)
//
#include <hip/hip_runtime.h>

#define NN 200000
#define NE 5000000
#define DIN 128
#define HID 16
#define DOUT 2

// ---------------- degree / normalization ----------------

__global__ void init_deg(float* deg) {
    int i = blockIdx.x * blockDim.x + threadIdx.x;
    if (i < NN) deg[i] = 1.0f;  // self-loop
}

__global__ void count_deg(const int* __restrict__ dst, float* deg) {
    int i = blockIdx.x * blockDim.x + threadIdx.x;
    if (i < NE) atomicAdd(&deg[dst[i]], 1.0f);
}

__global__ void make_dis(float* deg) {
    int i = blockIdx.x * blockDim.x + threadIdx.x;
    if (i < NN) deg[i] = rsqrtf(deg[i]);  // deg >= 1 always (self-loop)
}

__global__ void make_norm(const int* __restrict__ src, const int* __restrict__ dst,
                          const float* __restrict__ dis, float* __restrict__ norm) {
    int i = blockIdx.x * blockDim.x + threadIdx.x;
    if (i < NE) norm[i] = dis[src[i]] * dis[dst[i]];
}

// ---------------- dense GEMMs (feature transforms) ----------------

// out[N,16] = x[N,128] @ W[128,16].  block = 256 threads = 16 rows x 16 cols.
__global__ __launch_bounds__(256) void gemm_x_w1(const float* __restrict__ x,
                                                 const float* __restrict__ W,
                                                 float* __restrict__ out) {
    __shared__ float w[DIN * HID];  // 8 KB
    for (int t = threadIdx.x; t < DIN * HID; t += 256) w[t] = W[t];
    __syncthreads();
    int row = blockIdx.x * 16 + (threadIdx.x >> 4);
    int c = threadIdx.x & 15;
    if (row >= NN) return;
    const float4* xr = reinterpret_cast<const float4*>(x + (size_t)row * DIN);
    float acc = 0.f;
#pragma unroll
    for (int k4 = 0; k4 < DIN / 4; ++k4) {
        float4 v = xr[k4];
        acc += v.x * w[(4 * k4 + 0) * HID + c];
        acc += v.y * w[(4 * k4 + 1) * HID + c];
        acc += v.z * w[(4 * k4 + 2) * HID + c];
        acc += v.w * w[(4 * k4 + 3) * HID + c];
    }
    out[row * HID + c] = acc;
}

// out[N,16] = h[N,16] @ W[16,16]
__global__ __launch_bounds__(256) void gemm_h_w16(const float* __restrict__ h,
                                                  const float* __restrict__ W,
                                                  float* __restrict__ out) {
    __shared__ float w[HID * HID];
    if (threadIdx.x < HID * HID) w[threadIdx.x] = W[threadIdx.x];
    __syncthreads();
    int row = blockIdx.x * 16 + (threadIdx.x >> 4);
    int c = threadIdx.x & 15;
    if (row >= NN) return;
    const float4* hr = reinterpret_cast<const float4*>(h + (size_t)row * HID);
    float acc = 0.f;
#pragma unroll
    for (int k4 = 0; k4 < HID / 4; ++k4) {
        float4 v = hr[k4];
        acc += v.x * w[(4 * k4 + 0) * HID + c];
        acc += v.y * w[(4 * k4 + 1) * HID + c];
        acc += v.z * w[(4 * k4 + 2) * HID + c];
        acc += v.w * w[(4 * k4 + 3) * HID + c];
    }
    out[row * HID + c] = acc;
}

// out[N,2] = h[N,16] @ W[16,2]
__global__ __launch_bounds__(256) void gemm_h_w2(const float* __restrict__ h,
                                                 const float* __restrict__ W,
                                                 float* __restrict__ out) {
    int t = blockIdx.x * 256 + threadIdx.x;
    int row = t >> 1;
    int c = t & 1;
    if (row >= NN) return;
    const float* hr = h + (size_t)row * HID;
    float acc = 0.f;
#pragma unroll
    for (int k = 0; k < HID; ++k) acc += hr[k] * W[k * DOUT + c];
    out[row * DOUT + c] = acc;
}

// ---------------- aggregation ----------------

// agg[i][c] = xw[i][c] * dis[i]^2   (self-loop term, also zero-initializes)
__global__ void init_agg16(const float* __restrict__ xw, const float* __restrict__ dis,
                           float* __restrict__ agg) {
    int t = blockIdx.x * blockDim.x + threadIdx.x;
    int row = t >> 4;
    if (row >= NN) return;
    float d = dis[row];
    agg[t] = xw[t] * d * d;
}

__global__ void init_agg2(const float* __restrict__ xw, const float* __restrict__ dis,
                          float* __restrict__ agg) {
    int t = blockIdx.x * blockDim.x + threadIdx.x;
    int row = t >> 1;
    if (row >= NN) return;
    float d = dis[row];
    agg[t] = xw[t] * d * d;
}

// 16 lanes per edge: lane c does agg[dst][c] += xw[src][c] * norm[e]
__global__ __launch_bounds__(256) void edge_agg16(const int* __restrict__ src,
                                                  const int* __restrict__ dst,
                                                  const float* __restrict__ norm,
                                                  const float* __restrict__ xw,
                                                  float* agg) {
    int t = blockIdx.x * 256 + threadIdx.x;
    int e = t >> 4;
    int c = t & 15;
    if (e >= NE) return;
    int s = src[e];
    int d = dst[e];
    float v = xw[s * HID + c] * norm[e];
    atomicAdd(&agg[d * HID + c], v);
}

// one thread per edge, both output channels
__global__ __launch_bounds__(256) void edge_agg2(const int* __restrict__ src,
                                                 const int* __restrict__ dst,
                                                 const float* __restrict__ norm,
                                                 const float* __restrict__ xw,
                                                 float* agg) {
    int e = blockIdx.x * 256 + threadIdx.x;
    if (e >= NE) return;
    int s = src[e];
    int d = dst[e];
    float nm = norm[e];
    float2 v = *reinterpret_cast<const float2*>(&xw[s * DOUT]);
    atomicAdd(&agg[d * DOUT + 0], v.x * nm);
    atomicAdd(&agg[d * DOUT + 1], v.y * nm);
}

// in-place: agg = relu(agg + b)
__global__ void bias_relu16(float* agg, const float* __restrict__ b) {
    int t = blockIdx.x * blockDim.x + threadIdx.x;
    if (t >= NN * HID) return;
    float v = agg[t] + b[t & 15];
    agg[t] = v > 0.f ? v : 0.f;
}

// in-place on d_out: add bias then 2-class log_softmax
__global__ void bias_logsoftmax2(float* out, const float* __restrict__ b) {
    int i = blockIdx.x * blockDim.x + threadIdx.x;
    if (i >= NN) return;
    float v0 = out[i * 2 + 0] + b[0];
    float v1 = out[i * 2 + 1] + b[1];
    float m = fmaxf(v0, v1);
    float lse = m + logf(__expf(v0 - m) + __expf(v1 - m));
    reinterpret_cast<float2*>(out)[i] = make_float2(v0 - lse, v1 - lse);
}

// ---------------- launch ----------------

extern "C" void kernel_launch(void* const* d_in, const int* in_sizes, int n_in,
                              void* d_out, int out_size, void* d_ws, size_t ws_size,
                              hipStream_t stream) {
    const float* x = (const float*)d_in[0];
    const int* ei = (const int*)d_in[1];
    const float* W1 = (const float*)d_in[2];
    const float* b1 = (const float*)d_in[3];
    const float* W3 = (const float*)d_in[4];
    const float* b3 = (const float*)d_in[5];
    const float* W2 = (const float*)d_in[6];
    const float* b2 = (const float*)d_in[7];
    float* out = (float*)d_out;

    const int* src = ei;       // edge_index[0]
    const int* dst = ei + NE;  // edge_index[1]

    // workspace layout (floats)
    float* ws = (float*)d_ws;
    float* dis = ws;                 // N
    float* norm = dis + NN;          // E
    float* bufA = norm + NE;         // 16N
    float* bufB = bufA + NN * HID;   // 16N

    const int B = 256;
    auto cdiv = [](long long a, long long b) { return (int)((a + b - 1) / b); };

    // normalization
    init_deg<<<cdiv(NN, B), B, 0, stream>>>(dis);
    count_deg<<<cdiv(NE, B), B, 0, stream>>>(dst, dis);
    make_dis<<<cdiv(NN, B), B, 0, stream>>>(dis);
    make_norm<<<cdiv(NE, B), B, 0, stream>>>(src, dst, dis, norm);

    // conv1: bufA = x@W1 ; bufB = agg ; relu(+b1) -> h1 in bufB
    gemm_x_w1<<<cdiv(NN, 16), B, 0, stream>>>(x, W1, bufA);
    init_agg16<<<cdiv((long long)NN * HID, B), B, 0, stream>>>(bufA, dis, bufB);
    edge_agg16<<<cdiv((long long)NE * HID, B), B, 0, stream>>>(src, dst, norm, bufA, bufB);
    bias_relu16<<<cdiv((long long)NN * HID, B), B, 0, stream>>>(bufB, b1);

    // conv3: bufA = h1@W3 ; bufB = agg ; relu(+b3) -> h2 in bufB
    gemm_h_w16<<<cdiv(NN, 16), B, 0, stream>>>(bufB, W3, bufA);
    init_agg16<<<cdiv((long long)NN * HID, B), B, 0, stream>>>(bufA, dis, bufB);
    edge_agg16<<<cdiv((long long)NE * HID, B), B, 0, stream>>>(src, dst, norm, bufA, bufB);
    bias_relu16<<<cdiv((long long)NN * HID, B), B, 0, stream>>>(bufB, b3);

    // conv2: bufA[0:2N] = h2@W2 ; d_out = agg ; +b2 ; log_softmax
    gemm_h_w2<<<cdiv((long long)NN * DOUT, B), B, 0, stream>>>(bufB, W2, bufA);
    init_agg2<<<cdiv((long long)NN * DOUT, B), B, 0, stream>>>(bufA, dis, out);
    edge_agg2<<<cdiv(NE, B), B, 0, stream>>>(src, dst, norm, bufA, out);
    bias_logsoftmax2<<<cdiv(NN, B), B, 0, stream>>>(out, b2);
}

// Round 2
// 1399.360 us; speedup vs baseline: 1.0019x; 1.0019x over previous
//
#include <hip/hip_runtime.h>

#define NN 200000
#define NE 5000000
#define DIN 128
#define HID 16
#define DOUT 2

// ---------------- degree / normalization ----------------

__global__ void init_deg(float* deg) {
    int i = blockIdx.x * blockDim.x + threadIdx.x;
    if (i < NN) deg[i] = 1.0f;  // self-loop
}

__global__ void count_deg(const int* __restrict__ dst, float* deg) {
    int i = blockIdx.x * blockDim.x + threadIdx.x;
    if (i < NE) atomicAdd(&deg[dst[i]], 1.0f);
}

__global__ void make_dis(float* deg) {
    int i = blockIdx.x * blockDim.x + threadIdx.x;
    if (i < NN) deg[i] = rsqrtf(deg[i]);  // deg >= 1 always (self-loop)
}

__global__ void make_norm(const int* __restrict__ src, const int* __restrict__ dst,
                          const float* __restrict__ dis, float* __restrict__ norm) {
    int i = blockIdx.x * blockDim.x + threadIdx.x;
    if (i < NE) norm[i] = dis[src[i]] * dis[dst[i]];
}

// ---------------- dense GEMMs (feature transforms) ----------------

// out[N,16] = x[N,128] @ W[128,16].  block = 256 threads = 16 rows x 16 cols.
__global__ __launch_bounds__(256) void gemm_x_w1(const float* __restrict__ x,
                                                 const float* __restrict__ W,
                                                 float* __restrict__ out) {
    __shared__ float w[DIN * HID];  // 8 KB
    for (int t = threadIdx.x; t < DIN * HID; t += 256) w[t] = W[t];
    __syncthreads();
    int row = blockIdx.x * 16 + (threadIdx.x >> 4);
    int c = threadIdx.x & 15;
    if (row >= NN) return;
    const float4* xr = reinterpret_cast<const float4*>(x + (size_t)row * DIN);
    float acc = 0.f;
#pragma unroll
    for (int k4 = 0; k4 < DIN / 4; ++k4) {
        float4 v = xr[k4];
        acc += v.x * w[(4 * k4 + 0) * HID + c];
        acc += v.y * w[(4 * k4 + 1) * HID + c];
        acc += v.z * w[(4 * k4 + 2) * HID + c];
        acc += v.w * w[(4 * k4 + 3) * HID + c];
    }
    out[row * HID + c] = acc;
}

// out[N,16] = h[N,16] @ W[16,16]
__global__ __launch_bounds__(256) void gemm_h_w16(const float* __restrict__ h,
                                                  const float* __restrict__ W,
                                                  float* __restrict__ out) {
    __shared__ float w[HID * HID];
    if (threadIdx.x < HID * HID) w[threadIdx.x] = W[threadIdx.x];
    __syncthreads();
    int row = blockIdx.x * 16 + (threadIdx.x >> 4);
    int c = threadIdx.x & 15;
    if (row >= NN) return;
    const float4* hr = reinterpret_cast<const float4*>(h + (size_t)row * HID);
    float acc = 0.f;
#pragma unroll
    for (int k4 = 0; k4 < HID / 4; ++k4) {
        float4 v = hr[k4];
        acc += v.x * w[(4 * k4 + 0) * HID + c];
        acc += v.y * w[(4 * k4 + 1) * HID + c];
        acc += v.z * w[(4 * k4 + 2) * HID + c];
        acc += v.w * w[(4 * k4 + 3) * HID + c];
    }
    out[row * HID + c] = acc;
}

// out[N,2] = h[N,16] @ W[16,2]
__global__ __launch_bounds__(256) void gemm_h_w2(const float* __restrict__ h,
                                                 const float* __restrict__ W,
                                                 float* __restrict__ out) {
    int t = blockIdx.x * 256 + threadIdx.x;
    int row = t >> 1;
    int c = t & 1;
    if (row >= NN) return;
    const float* hr = h + (size_t)row * HID;
    float acc = 0.f;
#pragma unroll
    for (int k = 0; k < HID; ++k) acc += hr[k] * W[k * DOUT + c];
    out[row * DOUT + c] = acc;
}

// ---------------- aggregation ----------------

// agg[i][c] = xw[i][c] * dis[i]^2   (self-loop term, also zero-initializes)
__global__ void init_agg16(const float* __restrict__ xw, const float* __restrict__ dis,
                           float* __restrict__ agg) {
    int t = blockIdx.x * blockDim.x + threadIdx.x;
    int row = t >> 4;
    if (row >= NN) return;
    float d = dis[row];
    agg[t] = xw[t] * d * d;
}

__global__ void init_agg2(const float* __restrict__ xw, const float* __restrict__ dis,
                          float* __restrict__ agg) {
    int t = blockIdx.x * blockDim.x + threadIdx.x;
    int row = t >> 1;
    if (row >= NN) return;
    float d = dis[row];
    agg[t] = xw[t] * d * d;
}

// 16 lanes per edge: lane c does agg[dst][c] += xw[src][c] * norm[e]
__global__ __launch_bounds__(256) void edge_agg16(const int* __restrict__ src,
                                                  const int* __restrict__ dst,
                                                  const float* __restrict__ norm,
                                                  const float* __restrict__ xw,
                                                  float* agg) {
    int t = blockIdx.x * 256 + threadIdx.x;
    int e = t >> 4;
    int c = t & 15;
    if (e >= NE) return;
    int s = src[e];
    int d = dst[e];
    float v = xw[s * HID + c] * norm[e];
    atomicAdd(&agg[d * HID + c], v);
}

// one thread per edge, both output channels — into WORKSPACE (L2-cached
// atomics), never into d_out (fine-grained memory: each atomic = 32B HBM write)
__global__ __launch_bounds__(256) void edge_agg2(const int* __restrict__ src,
                                                 const int* __restrict__ dst,
                                                 const float* __restrict__ norm,
                                                 const float* __restrict__ xw,
                                                 float* agg) {
    int e = blockIdx.x * 256 + threadIdx.x;
    if (e >= NE) return;
    int s = src[e];
    int d = dst[e];
    float nm = norm[e];
    float2 v = *reinterpret_cast<const float2*>(&xw[s * DOUT]);
    atomicAdd(&agg[d * DOUT + 0], v.x * nm);
    atomicAdd(&agg[d * DOUT + 1], v.y * nm);
}

// in-place: agg = relu(agg + b)
__global__ void bias_relu16(float* agg, const float* __restrict__ b) {
    int t = blockIdx.x * blockDim.x + threadIdx.x;
    if (t >= NN * HID) return;
    float v = agg[t] + b[t & 15];
    agg[t] = v > 0.f ? v : 0.f;
}

// read agg2 from ws, add bias, 2-class log_softmax, plain coalesced store to d_out
__global__ void bias_logsoftmax2(const float* __restrict__ agg, float* __restrict__ out,
                                 const float* __restrict__ b) {
    int i = blockIdx.x * blockDim.x + threadIdx.x;
    if (i >= NN) return;
    float2 v = reinterpret_cast<const float2*>(agg)[i];
    float v0 = v.x + b[0];
    float v1 = v.y + b[1];
    float m = fmaxf(v0, v1);
    float lse = m + logf(__expf(v0 - m) + __expf(v1 - m));
    reinterpret_cast<float2*>(out)[i] = make_float2(v0 - lse, v1 - lse);
}

// ---------------- launch ----------------

extern "C" void kernel_launch(void* const* d_in, const int* in_sizes, int n_in,
                              void* d_out, int out_size, void* d_ws, size_t ws_size,
                              hipStream_t stream) {
    const float* x = (const float*)d_in[0];
    const int* ei = (const int*)d_in[1];
    const float* W1 = (const float*)d_in[2];
    const float* b1 = (const float*)d_in[3];
    const float* W3 = (const float*)d_in[4];
    const float* b3 = (const float*)d_in[5];
    const float* W2 = (const float*)d_in[6];
    const float* b2 = (const float*)d_in[7];
    float* out = (float*)d_out;

    const int* src = ei;       // edge_index[0]
    const int* dst = ei + NE;  // edge_index[1]

    // workspace layout (floats)
    float* ws = (float*)d_ws;
    float* dis = ws;                 // N
    float* norm = dis + NN;          // E
    float* bufA = norm + NE;         // 16N
    float* bufB = bufA + NN * HID;   // 16N

    const int B = 256;
    auto cdiv = [](long long a, long long b) { return (int)((a + b - 1) / b); };

    // normalization
    init_deg<<<cdiv(NN, B), B, 0, stream>>>(dis);
    count_deg<<<cdiv(NE, B), B, 0, stream>>>(dst, dis);
    make_dis<<<cdiv(NN, B), B, 0, stream>>>(dis);
    make_norm<<<cdiv(NE, B), B, 0, stream>>>(src, dst, dis, norm);

    // conv1: bufA = x@W1 ; bufB = agg ; relu(+b1) -> h1 in bufB
    gemm_x_w1<<<cdiv(NN, 16), B, 0, stream>>>(x, W1, bufA);
    init_agg16<<<cdiv((long long)NN * HID, B), B, 0, stream>>>(bufA, dis, bufB);
    edge_agg16<<<cdiv((long long)NE * HID, B), B, 0, stream>>>(src, dst, norm, bufA, bufB);
    bias_relu16<<<cdiv((long long)NN * HID, B), B, 0, stream>>>(bufB, b1);

    // conv3: bufA = h1@W3 ; bufB = agg ; relu(+b3) -> h2 in bufB
    gemm_h_w16<<<cdiv(NN, 16), B, 0, stream>>>(bufB, W3, bufA);
    init_agg16<<<cdiv((long long)NN * HID, B), B, 0, stream>>>(bufA, dis, bufB);
    edge_agg16<<<cdiv((long long)NE * HID, B), B, 0, stream>>>(src, dst, norm, bufA, bufB);
    bias_relu16<<<cdiv((long long)NN * HID, B), B, 0, stream>>>(bufB, b3);

    // conv2: bufA[0:2N] = h2@W2 ; agg2 lives in the (now dead) bufB region
    float* agg2 = bufB;  // bufB's h2 is consumed by gemm_h_w2 before agg starts
    gemm_h_w2<<<cdiv((long long)NN * DOUT, B), B, 0, stream>>>(bufB, W2, bufA);
    init_agg2<<<cdiv((long long)NN * DOUT, B), B, 0, stream>>>(bufA, dis, agg2);
    edge_agg2<<<cdiv(NE, B), B, 0, stream>>>(src, dst, norm, bufA, agg2);
    bias_logsoftmax2<<<cdiv(NN, B), B, 0, stream>>>(agg2, out, b2);
}